// Round 14
// baseline (177.456 us; speedup 1.0000x reference)
//
#include <hip/hip_runtime.h>

// RWKV-5 WKV via chunked linear attention + MFMA, LDS bf16 tiles.
// B=4, T=4096, H=32, S=64. State scaled: X = s_raw*SCALE (X' = td*X + k (x) v').
// Subchunk L=64: out = [strictTril(RW@KW^T) + diag]@VS + RW@X0
//                X_L = td^64 * (X0 + KW^T@VS)
//   RW[i][s]=r_i[s]*td^i, KW[j][s]=k_j[s]*td^-(j+1), diag_i = sum_s r_i tf k_i
// Round 14 = best-of recombination: r13's wave-specialized pass1 (win ~-11us)
// + r12's pass2 (in-place partial->entry conversion) + r12's pass3 (no fused
// prefix -- r13 showed it costs pass3 +10us paid 1024x vs pass2's 128x).

namespace {
constexpr int cB = 4, cT = 4096, cH = 32, cS = 64;
constexpr int cTS = cH * cS;                 // 2048
constexpr float cScale = 1.0f / 128.0f;
constexpr int cSC = 8, cSCL = cT / cSC;      // 8 superchunks of 512
constexpr int cL = 64, cNS = cSCL / cL;      // 8 subchunks of 64
constexpr int cBH = cB * cH;                 // 128
}

typedef float  v2f   __attribute__((ext_vector_type(2)));
typedef __bf16 bf16x8 __attribute__((ext_vector_type(8)));
typedef float  f32x16 __attribute__((ext_vector_type(16)));
typedef unsigned short u16x4 __attribute__((ext_vector_type(4)));
typedef unsigned short u16x8 __attribute__((ext_vector_type(8)));
typedef unsigned int   u32x2 __attribute__((ext_vector_type(2)));
typedef unsigned int   u32x4 __attribute__((ext_vector_type(4)));

#define BARRIER() asm volatile("s_waitcnt lgkmcnt(0)\n\ts_barrier" ::: "memory")

__device__ __forceinline__ float hw_log2(float x) { return __builtin_amdgcn_logf(x); }
__device__ __forceinline__ float hw_exp2(float x) { return __builtin_amdgcn_exp2f(x); }

// generic tile swizzle (RW/KW): fine for row stores + row/col reads
__device__ __forceinline__ int swzb(int row, int byteInRow) {
    return row * 128 + (byteInRow ^ ((row & 15) << 3));
}
// VST swizzle: column stores (col ~ wave-constant) need full row-octet spread
__device__ __forceinline__ int swzbV(int row, int byteInRow) {
    return row * 128 + (byteInRow ^ ((row & 15) << 3) ^ (((row >> 3) & 7) << 4));
}
__device__ __forceinline__ int crow(int r, int hi) {
    return (r & 3) + 8 * (r >> 2) + 4 * hi;               // 32x32 C-layout row
}
__device__ __forceinline__ unsigned short bfb(float x) {
    return __builtin_bit_cast(unsigned short, (__bf16)x);
}
__device__ __forceinline__ bf16x8 ldRowFrag(const unsigned short* T, int row, int col) {
    const char* p = (const char*)T;
    u16x4 a = *(const u16x4*)(p + swzb(row, col * 2));
    u16x4 b = *(const u16x4*)(p + swzb(row, col * 2 + 8));
    u16x8 r = {a[0], a[1], a[2], a[3], b[0], b[1], b[2], b[3]};
    return __builtin_bit_cast(bf16x8, r);
}
__device__ __forceinline__ bf16x8 ldRowFragV(const unsigned short* T, int row, int col) {
    const char* p = (const char*)T;
    u16x4 a = *(const u16x4*)(p + swzbV(row, col * 2));
    u16x4 b = *(const u16x4*)(p + swzbV(row, col * 2 + 8));
    u16x8 r = {a[0], a[1], a[2], a[3], b[0], b[1], b[2], b[3]};
    return __builtin_bit_cast(bf16x8, r);
}
__device__ __forceinline__ bf16x8 ldColFrag(const unsigned short* T, int row0, int col) {
    const char* p = (const char*)T;
    u16x8 r;
#pragma unroll
    for (int e = 0; e < 8; ++e)
        r[e] = *(const unsigned short*)(p + swzb(row0 + e, col * 2));
    return __builtin_bit_cast(bf16x8, r);
}
__device__ __forceinline__ void stRow8(unsigned short* T, int row, int col, u16x8 v) {
    char* p = (char*)T;
    u16x4 a = {v[0], v[1], v[2], v[3]}, b = {v[4], v[5], v[6], v[7]};
    *(u16x4*)(p + swzb(row, col * 2)) = a;
    *(u16x4*)(p + swzb(row, col * 2 + 8)) = b;
}
__device__ __forceinline__ void stElV16(unsigned short* T, int row, int col,
                                        unsigned short v) {
    *(unsigned short*)((char*)T + swzbV(row, col * 2)) = v;
}
__device__ __forceinline__ unsigned cvtpk(float a, float b) {
    unsigned r;
    asm("v_cvt_pk_bf16_f32 %0, %1, %2" : "=v"(r) : "v"(a), "v"(b));
    return r;
}
// Repack an f32x16 C-layout accumulator (lane = c-col, regs = c-rows) into two
// MFMA operand frags covering k-rows [0,16) and [16,32). Verified on HW (r8).
__device__ __forceinline__ void pack2(const f32x16& m, bf16x8& f0, bf16x8& f1) {
#pragma unroll
    for (int g2 = 0; g2 < 2; ++g2) {
        const int bs = 8 * g2;
        unsigned A0 = cvtpk(m[bs + 0], m[bs + 1]);
        unsigned A1 = cvtpk(m[bs + 2], m[bs + 3]);
        unsigned B0 = cvtpk(m[bs + 4], m[bs + 5]);
        unsigned B1 = cvtpk(m[bs + 6], m[bs + 7]);
        u32x2 r0 = __builtin_amdgcn_permlane32_swap(A0, B0, false, false);
        u32x2 r1 = __builtin_amdgcn_permlane32_swap(A1, B1, false, false);
        u32x4 w = {r0[0], r1[0], r0[1], r1[1]};
        if (g2 == 0) f0 = __builtin_bit_cast(bf16x8, w);
        else         f1 = __builtin_bit_cast(bf16x8, w);
    }
}

// ---- pass1: from-zero superchunk partials (sc 0..6), wave-specialized ------
__global__ __launch_bounds__(512)
void rwkv5_pass1(const float* __restrict__ K, const float* __restrict__ V,
                 const float* __restrict__ TD, float* __restrict__ Buf) {
    __shared__ alignas(16) unsigned short KWs[2][4096], VSTs[2][4096];
    const int bh = blockIdx.x, sc = blockIdx.y;
    const int b = bh >> 5, h = bh & 31;
    const int tid = threadIdx.x, wid = tid >> 6, l = tid & 63;
    const int lo = l & 31, hi = l >> 5;
    // compute roles (wid 0..3)
    const int dhs = (wid >> 1) & 1, shs = wid & 1;
    const int dS = lo + 32 * dhs, sS = lo + 32 * shs;
    // stage roles (wid 4..7): 256 staging threads, 16 elems each
    const int sid = tid - 256;
    const int st = (sid & 255) >> 2, c16 = (sid & 3) * 16;
    const size_t tbase = ((size_t)b * cT + (size_t)sc * cSCL) * cTS + h * cS;
    const float *kb = K + tbase, *vb = V + tbase;

    float ipw[16];
    float tdL = 1.0f;
    if (wid >= 4) {
#pragma unroll
        for (int e = 0; e < 16; ++e) {
            const float l2 = hw_log2(TD[h * cS + c16 + e]);
            ipw[e] = hw_exp2(-(float)(st + 1) * l2);     // td^-(st+1)
        }
    } else {
        tdL = TD[h * cS + sS];
#pragma unroll
        for (int i = 0; i < 6; ++i) tdL *= tdL;          // td^64
    }

    float kx[16], vx[16];
    auto gload = [&](int cc) {
        const size_t off = ((size_t)(cc * cL + st)) * cTS + c16;
#pragma unroll
        for (int i = 0; i < 4; ++i) {
            *(float4*)&kx[i * 4] = *(const float4*)(kb + off + i * 4);
            *(float4*)&vx[i * 4] = *(const float4*)(vb + off + i * 4);
        }
    };
    auto tileWrite = [&](int bi) {
        const v2f* kx2  = (const v2f*)kx;
        const v2f* vx2  = (const v2f*)vx;
        const v2f* ipw2 = (const v2f*)ipw;
        u16x8 w;
#pragma unroll
        for (int hf = 0; hf < 2; ++hf) {
#pragma unroll
            for (int e2 = 0; e2 < 4; ++e2) {
                v2f m = kx2[hf * 4 + e2] * ipw2[hf * 4 + e2];
                w[2 * e2]     = bfb(m.x);
                w[2 * e2 + 1] = bfb(m.y);
            }
            stRow8(KWs[bi], st, c16 + hf * 8, w);
        }
        const v2f sc2 = {cScale, cScale};
#pragma unroll
        for (int e2 = 0; e2 < 8; ++e2) {
            v2f m = vx2[e2] * sc2;
            stElV16(VSTs[bi], c16 + 2 * e2,     st, bfb(m.x));
            stElV16(VSTs[bi], c16 + 2 * e2 + 1, st, bfb(m.y));
        }
    };

    f32x16 x;
#pragma unroll
    for (int i = 0; i < 16; ++i) x[i] = 0.f;

    if (wid >= 4) { gload(0); tileWrite(0); gload(1); }
    BARRIER();
#pragma unroll 1
    for (int c = 0; c < cNS; ++c) {
        const int cur = c & 1, nxt = cur ^ 1;
        if (wid < 4) {
            f32x16 w;
#pragma unroll
            for (int i = 0; i < 16; ++i) w[i] = 0.f;
            __builtin_amdgcn_s_setprio(1);
#pragma unroll
            for (int ks = 0; ks < 4; ++ks) {
                bf16x8 vaf = ldRowFragV(VSTs[cur], dS, ks * 16 + hi * 8);
                bf16x8 kcf = ldColFrag(KWs[cur], ks * 16 + hi * 8, sS);
                w = __builtin_amdgcn_mfma_f32_32x32x16_bf16(vaf, kcf, w, 0, 0, 0);
            }
            __builtin_amdgcn_s_setprio(0);
#pragma unroll
            for (int i = 0; i < 16; ++i) x[i] = tdL * (x[i] + w[i]);
        } else {
            if (c + 1 < cNS) tileWrite(nxt);
            if (c + 2 < cNS) gload(c + 2);
        }
        BARRIER();
    }
    if (wid < 4) {
        float* xp = Buf + ((size_t)bh * cSC + sc) * cS * cS;
#pragma unroll
        for (int r = 0; r < 16; ++r)
            xp[(size_t)sS * cS + crow(r, hi) + 32 * dhs] = x[r];
    }
}

// ---------------- pass2: propagate entry states (in place) ------------------
__global__ __launch_bounds__(256)
void rwkv5_pass2(const float* __restrict__ S2in, const float* __restrict__ TD,
                 float* __restrict__ Buf) {
    const int bh = blockIdx.x, h = bh & 31;
    const int t = threadIdx.x, s = t >> 2, db = (t & 3) * 16;
    float d = TD[h * cS + s];
#pragma unroll
    for (int i = 0; i < 9; ++i) d *= d;               // td^512
    float4 x[4];
    const float* s0 = S2in + ((size_t)bh * cS + s) * cS + db;
#pragma unroll
    for (int i = 0; i < 4; ++i) {
        x[i] = *(const float4*)(s0 + i * 4);
        x[i].x *= cScale; x[i].y *= cScale; x[i].z *= cScale; x[i].w *= cScale;
    }
    for (int sc = 0; sc < cSC; ++sc) {
        float* base = Buf + (((size_t)bh * cSC + sc) * cS + s) * cS + db;
        float4 pr[4];
        if (sc < cSC - 1) {
#pragma unroll
            for (int i = 0; i < 4; ++i) pr[i] = *(const float4*)(base + i * 4);
        }
#pragma unroll
        for (int i = 0; i < 4; ++i) *(float4*)(base + i * 4) = x[i];
        if (sc < cSC - 1) {
#pragma unroll
            for (int i = 0; i < 4; ++i) {
                x[i].x = fmaf(d, x[i].x, pr[i].x);
                x[i].y = fmaf(d, x[i].y, pr[i].y);
                x[i].z = fmaf(d, x[i].z, pr[i].z);
                x[i].w = fmaf(d, x[i].w, pr[i].w);
            }
        }
    }
}

// ---------------- pass3: main compute ----------------------------------------
__global__ __launch_bounds__(512)
void rwkv5_pass3(const float* __restrict__ K, const float* __restrict__ V,
                 const float* __restrict__ R, const float* __restrict__ TF,
                 const float* __restrict__ TD, const float* __restrict__ Buf,
                 float* __restrict__ Out) {
    __shared__ alignas(16) unsigned short RWs[2][4096], KWs[2][4096],
                                          VSTs[2][4096];
    __shared__ alignas(16) u32x4 XTF[2][2][4][64];   // [buf][dh][ks][lane]
    __shared__ float DIAGs[2][64];
    const int u = blockIdx.x, bh = u >> 3, sc = u & 7;
    const int b = bh >> 5, h = bh & 31;
    const int tid = threadIdx.x, wid = tid >> 6, l = tid & 63;
    const int lo = l & 31, hi = l >> 5;
    const size_t tbase = ((size_t)b * cT + (size_t)sc * cSCL) * cTS + h * cS;
    const float *kb = K + tbase, *vb = V + tbase, *rb = R + tbase;
    float* ob = Out + tbase;

    // staging role: row st (timestep), 8 cols at sc8
    const int st = tid >> 3, sc8 = (tid & 7) * 8;
    float pwA[8], ipwB[8], tfv[8];
#pragma unroll
    for (int e = 0; e < 8; ++e) {
        const float l2 = hw_log2(TD[h * cS + sc8 + e]);
        pwA[e]  = hw_exp2((float)st * l2);            // td^st
        ipwB[e] = hw_exp2(-(float)(st + 1) * l2);     // td^-(st+1)
        tfv[e]  = TF[h * cS + sc8 + e];
    }
    float kx[8], vx[8], rx[8];
    auto gload = [&](int cc) {
        const size_t off = ((size_t)(cc * cL + st)) * cTS + sc8;
        *(float4*)&kx[0] = *(const float4*)(kb + off);
        *(float4*)&kx[4] = *(const float4*)(kb + off + 4);
        *(float4*)&vx[0] = *(const float4*)(vb + off);
        *(float4*)&vx[4] = *(const float4*)(vb + off + 4);
        *(float4*)&rx[0] = *(const float4*)(rb + off);
        *(float4*)&rx[4] = *(const float4*)(rb + off + 4);
    };
    auto tileWrite = [&](int bi) {
        const v2f* kx2  = (const v2f*)kx;
        const v2f* rx2  = (const v2f*)rx;
        const v2f* vx2  = (const v2f*)vx;
        const v2f* pwA2 = (const v2f*)pwA;
        const v2f* ipw2 = (const v2f*)ipwB;
        const v2f* tf2  = (const v2f*)tfv;
        u16x8 w;
#pragma unroll
        for (int e2 = 0; e2 < 4; ++e2) {
            v2f m = rx2[e2] * pwA2[e2];
            w[2 * e2]     = bfb(m.x);
            w[2 * e2 + 1] = bfb(m.y);
        }
        stRow8(RWs[bi], st, sc8, w);
#pragma unroll
        for (int e2 = 0; e2 < 4; ++e2) {
            v2f m = kx2[e2] * ipw2[e2];
            w[2 * e2]     = bfb(m.x);
            w[2 * e2 + 1] = bfb(m.y);
        }
        stRow8(KWs[bi], st, sc8, w);
        const v2f sc2 = {cScale, cScale};
#pragma unroll
        for (int e2 = 0; e2 < 4; ++e2) {
            v2f m = vx2[e2] * sc2;
            stElV16(VSTs[bi], sc8 + 2 * e2,     st, bfb(m.x));
            stElV16(VSTs[bi], sc8 + 2 * e2 + 1, st, bfb(m.y));
        }
        v2f p2 = {0.f, 0.f};
#pragma unroll
        for (int e2 = 0; e2 < 4; ++e2)
            p2 = (rx2[e2] * kx2[e2]) * tf2[e2] + p2;
        float p = p2.x + p2.y;
        p += __shfl_xor(p, 1, 64);
        p += __shfl_xor(p, 2, 64);
        p += __shfl_xor(p, 4, 64);
        if ((tid & 7) == 0) DIAGs[bi][st] = p;
    };

    // GEMM-wave roles (wid 0..3): out quadrant rows 32*ih.., cols 32*dh..
    const int ih = (wid >> 1) & 1, dh = wid & 1;
    // state-wave roles (wid 4..7): X quadrant s-rows 32*shs.., d-cols 32*dhs..
    const int shs = (wid >> 1) & 1, dhs = wid & 1;

    f32x16 x;
    float tdLr[16];
    if (wid >= 4) {
        const float* xin = Buf + ((size_t)bh * cSC + sc) * cS * cS;
#pragma unroll
        for (int r = 0; r < 16; ++r) {
            const int s = crow(r, hi) + 32 * shs;
            x[r] = xin[(size_t)s * cS + lo + 32 * dhs];
            float t = TD[h * cS + s];
#pragma unroll
            for (int i = 0; i < 6; ++i) t *= t;       // td^64
            tdLr[r] = t;
        }
        bf16x8 f0, f1;
        pack2(x, f0, f1);
        XTF[0][dhs][2 * shs][l]     = __builtin_bit_cast(u32x4, f0);
        XTF[0][dhs][2 * shs + 1][l] = __builtin_bit_cast(u32x4, f1);
    }
    gload(0); tileWrite(0); gload(1);
    BARRIER();

#pragma unroll 1
    for (int c = 0; c < cNS; ++c) {
        const int cur = c & 1, nxt = cur ^ 1;
        if (wid < 4) {
            // ---- A^T blocks in-register ----
            bf16x8 rwf[4];
#pragma unroll
            for (int ks = 0; ks < 4; ++ks)
                rwf[ks] = ldRowFrag(RWs[cur], lo + 32 * ih, ks * 16 + hi * 8);
            bf16x8 af0, af1, af2, af3;
            if (ih == 1) {                     // unmasked block j in [0,32)
                f32x16 aU;
#pragma unroll
                for (int i = 0; i < 16; ++i) aU[i] = 0.f;
                __builtin_amdgcn_s_setprio(1);
#pragma unroll
                for (int ks = 0; ks < 4; ++ks) {
                    bf16x8 kwf = ldRowFrag(KWs[cur], lo, ks * 16 + hi * 8);
                    aU = __builtin_amdgcn_mfma_f32_32x32x16_bf16(kwf, rwf[ks], aU, 0, 0, 0);
                }
                __builtin_amdgcn_s_setprio(0);
                pack2(aU, af0, af1);
            }
            f32x16 aM;                         // diagonal block j in [32ih, 32ih+32)
#pragma unroll
            for (int i = 0; i < 16; ++i) aM[i] = 0.f;
            __builtin_amdgcn_s_setprio(1);
#pragma unroll
            for (int ks = 0; ks < 4; ++ks) {
                bf16x8 kwf = ldRowFrag(KWs[cur], lo + 32 * ih, ks * 16 + hi * 8);
                aM = __builtin_amdgcn_mfma_f32_32x32x16_bf16(kwf, rwf[ks], aM, 0, 0, 0);
            }
            __builtin_amdgcn_s_setprio(0);
            const float diagv = DIAGs[cur][lo + 32 * ih];
#pragma unroll
            for (int r = 0; r < 16; ++r) {
                const int cr = crow(r, hi);
                aM[r] = (lo > cr) ? aM[r] : ((lo == cr) ? diagv : 0.f);
            }
            if (ih == 1) pack2(aM, af2, af3);
            else         pack2(aM, af0, af1);
            // ---- out = A@VS + RW@X ----
            f32x16 o;
#pragma unroll
            for (int i = 0; i < 16; ++i) o[i] = 0.f;
            __builtin_amdgcn_s_setprio(1);
            o = __builtin_amdgcn_mfma_f32_32x32x16_bf16(
                af0, ldRowFragV(VSTs[cur], lo + 32 * dh, 0 * 16 + hi * 8), o, 0, 0, 0);
            o = __builtin_amdgcn_mfma_f32_32x32x16_bf16(
                af1, ldRowFragV(VSTs[cur], lo + 32 * dh, 1 * 16 + hi * 8), o, 0, 0, 0);
            if (ih == 1) {
                o = __builtin_amdgcn_mfma_f32_32x32x16_bf16(
                    af2, ldRowFragV(VSTs[cur], lo + 32 * dh, 2 * 16 + hi * 8), o, 0, 0, 0);
                o = __builtin_amdgcn_mfma_f32_32x32x16_bf16(
                    af3, ldRowFragV(VSTs[cur], lo + 32 * dh, 3 * 16 + hi * 8), o, 0, 0, 0);
            }
#pragma unroll
            for (int ks = 0; ks < 4; ++ks) {
                bf16x8 xf = __builtin_bit_cast(bf16x8, XTF[cur][dh][ks][l]);
                o = __builtin_amdgcn_mfma_f32_32x32x16_bf16(rwf[ks], xf, o, 0, 0, 0);
            }
            __builtin_amdgcn_s_setprio(0);
            const int t0 = c * cL;
#pragma unroll
            for (int r = 0; r < 16; ++r)
                ob[(size_t)(t0 + crow(r, hi) + 32 * ih) * cTS + 32 * dh + lo] = o[r];
        } else {
            // ---- state chain: w = KW^T @ VS, x in (lane=d, reg=s) layout ----
            f32x16 w;
#pragma unroll
            for (int i = 0; i < 16; ++i) w[i] = 0.f;
            __builtin_amdgcn_s_setprio(1);
#pragma unroll
            for (int ks = 0; ks < 4; ++ks) {
                bf16x8 kcf = ldColFrag(KWs[cur], ks * 16 + hi * 8, lo + 32 * shs);
                bf16x8 vaf = ldRowFragV(VSTs[cur], lo + 32 * dhs, ks * 16 + hi * 8);
                w = __builtin_amdgcn_mfma_f32_32x32x16_bf16(kcf, vaf, w, 0, 0, 0);
            }
            __builtin_amdgcn_s_setprio(0);
#pragma unroll
            for (int i = 0; i < 16; ++i) x[i] = tdLr[i] * (x[i] + w[i]);
            if (c + 1 < cNS) {
                bf16x8 f0, f1;
                pack2(x, f0, f1);
                XTF[nxt][dhs][2 * shs][l]     = __builtin_bit_cast(u32x4, f0);
                XTF[nxt][dhs][2 * shs + 1][l] = __builtin_bit_cast(u32x4, f1);
            }
        }
        if (c + 1 < cNS) tileWrite(nxt);
        if (c + 2 < cNS) gload(c + 2);
        BARRIER();
    }
    if (wid >= 4 && sc == cSC - 1) {
        float* o2 = Out + (size_t)cB * cT * cTS + (size_t)bh * cS * cS;
#pragma unroll
        for (int r = 0; r < 16; ++r) {
            const int s = crow(r, hi) + 32 * shs;
            o2[(size_t)s * cS + lo + 32 * dhs] = x[r] * 128.0f;
        }
    }
}

extern "C" void kernel_launch(void* const* d_in, const int* in_sizes, int n_in,
                              void* d_out, int out_size, void* d_ws,
                              size_t ws_size, hipStream_t stream) {
    const float* K    = (const float*)d_in[0];
    const float* V    = (const float*)d_in[1];
    const float* R    = (const float*)d_in[2];
    const float* S2in = (const float*)d_in[3];
    const float* TF   = (const float*)d_in[4];
    const float* TD   = (const float*)d_in[5];
    float* OutP = (float*)d_out;
    float* Buf  = (float*)d_ws;            // [128][8][64][64] f32 = 16.8 MB
    (void)in_sizes; (void)n_in; (void)ws_size; (void)out_size;

    rwkv5_pass1<<<dim3(cBH, cSC - 1), dim3(512), 0, stream>>>(K, V, TD, Buf);
    rwkv5_pass2<<<dim3(cBH), dim3(256), 0, stream>>>(S2in, TD, Buf);
    rwkv5_pass3<<<dim3(cBH * cSC), dim3(512), 0, stream>>>(K, V, R, TF, TD,
                                                           Buf, OutP);
}

// Round 15
// 160.323 us; speedup vs baseline: 1.1069x; 1.1069x over previous
//
#include <hip/hip_runtime.h>

// RWKV-5 WKV via chunked linear attention + MFMA, LDS bf16 tiles.
// B=4, T=4096, H=32, S=64. State scaled: X = s_raw*SCALE (X' = td*X + k (x) v').
// Subchunk L=64: out = [strictTril(RW@KW^T) + diag]@VS + RW@X0
//                X_L = td^64 * (X0 + KW^T@VS)
//   RW[i][s]=r_i[s]*td^i, KW[j][s]=k_j[s]*td^-(j+1), diag_i = sum_s r_i tf k_i
// Round 15 = round 14 with cSC 8 -> 4 (single-variable): pass1 re-reads 3/4
// instead of 7/8 of k,v and fits one dispatch round (384 blocks); pass3 runs
// 512 blocks x 16 subchunks (exactly 2 blocks/CU, half the prologues).
// pass2 decay updated td^512 -> td^1024 (10 squarings). Nothing else changed.

namespace {
constexpr int cB = 4, cT = 4096, cH = 32, cS = 64;
constexpr int cTS = cH * cS;                 // 2048
constexpr float cScale = 1.0f / 128.0f;
constexpr int cSC = 4, cSCL = cT / cSC;      // 4 superchunks of 1024
constexpr int cL = 64, cNS = cSCL / cL;      // 16 subchunks of 64
constexpr int cBH = cB * cH;                 // 128
}

typedef float  v2f   __attribute__((ext_vector_type(2)));
typedef __bf16 bf16x8 __attribute__((ext_vector_type(8)));
typedef float  f32x16 __attribute__((ext_vector_type(16)));
typedef unsigned short u16x4 __attribute__((ext_vector_type(4)));
typedef unsigned short u16x8 __attribute__((ext_vector_type(8)));
typedef unsigned int   u32x2 __attribute__((ext_vector_type(2)));
typedef unsigned int   u32x4 __attribute__((ext_vector_type(4)));

#define BARRIER() asm volatile("s_waitcnt lgkmcnt(0)\n\ts_barrier" ::: "memory")

__device__ __forceinline__ float hw_log2(float x) { return __builtin_amdgcn_logf(x); }
__device__ __forceinline__ float hw_exp2(float x) { return __builtin_amdgcn_exp2f(x); }

// generic tile swizzle (RW/KW): fine for row stores + row/col reads
__device__ __forceinline__ int swzb(int row, int byteInRow) {
    return row * 128 + (byteInRow ^ ((row & 15) << 3));
}
// VST swizzle: column stores (col ~ wave-constant) need full row-octet spread
__device__ __forceinline__ int swzbV(int row, int byteInRow) {
    return row * 128 + (byteInRow ^ ((row & 15) << 3) ^ (((row >> 3) & 7) << 4));
}
__device__ __forceinline__ int crow(int r, int hi) {
    return (r & 3) + 8 * (r >> 2) + 4 * hi;               // 32x32 C-layout row
}
__device__ __forceinline__ unsigned short bfb(float x) {
    return __builtin_bit_cast(unsigned short, (__bf16)x);
}
__device__ __forceinline__ bf16x8 ldRowFrag(const unsigned short* T, int row, int col) {
    const char* p = (const char*)T;
    u16x4 a = *(const u16x4*)(p + swzb(row, col * 2));
    u16x4 b = *(const u16x4*)(p + swzb(row, col * 2 + 8));
    u16x8 r = {a[0], a[1], a[2], a[3], b[0], b[1], b[2], b[3]};
    return __builtin_bit_cast(bf16x8, r);
}
__device__ __forceinline__ bf16x8 ldRowFragV(const unsigned short* T, int row, int col) {
    const char* p = (const char*)T;
    u16x4 a = *(const u16x4*)(p + swzbV(row, col * 2));
    u16x4 b = *(const u16x4*)(p + swzbV(row, col * 2 + 8));
    u16x8 r = {a[0], a[1], a[2], a[3], b[0], b[1], b[2], b[3]};
    return __builtin_bit_cast(bf16x8, r);
}
__device__ __forceinline__ bf16x8 ldColFrag(const unsigned short* T, int row0, int col) {
    const char* p = (const char*)T;
    u16x8 r;
#pragma unroll
    for (int e = 0; e < 8; ++e)
        r[e] = *(const unsigned short*)(p + swzb(row0 + e, col * 2));
    return __builtin_bit_cast(bf16x8, r);
}
__device__ __forceinline__ void stRow8(unsigned short* T, int row, int col, u16x8 v) {
    char* p = (char*)T;
    u16x4 a = {v[0], v[1], v[2], v[3]}, b = {v[4], v[5], v[6], v[7]};
    *(u16x4*)(p + swzb(row, col * 2)) = a;
    *(u16x4*)(p + swzb(row, col * 2 + 8)) = b;
}
__device__ __forceinline__ void stElV16(unsigned short* T, int row, int col,
                                        unsigned short v) {
    *(unsigned short*)((char*)T + swzbV(row, col * 2)) = v;
}
__device__ __forceinline__ unsigned cvtpk(float a, float b) {
    unsigned r;
    asm("v_cvt_pk_bf16_f32 %0, %1, %2" : "=v"(r) : "v"(a), "v"(b));
    return r;
}
// Repack an f32x16 C-layout accumulator (lane = c-col, regs = c-rows) into two
// MFMA operand frags covering k-rows [0,16) and [16,32). Verified on HW (r8).
__device__ __forceinline__ void pack2(const f32x16& m, bf16x8& f0, bf16x8& f1) {
#pragma unroll
    for (int g2 = 0; g2 < 2; ++g2) {
        const int bs = 8 * g2;
        unsigned A0 = cvtpk(m[bs + 0], m[bs + 1]);
        unsigned A1 = cvtpk(m[bs + 2], m[bs + 3]);
        unsigned B0 = cvtpk(m[bs + 4], m[bs + 5]);
        unsigned B1 = cvtpk(m[bs + 6], m[bs + 7]);
        u32x2 r0 = __builtin_amdgcn_permlane32_swap(A0, B0, false, false);
        u32x2 r1 = __builtin_amdgcn_permlane32_swap(A1, B1, false, false);
        u32x4 w = {r0[0], r1[0], r0[1], r1[1]};
        if (g2 == 0) f0 = __builtin_bit_cast(bf16x8, w);
        else         f1 = __builtin_bit_cast(bf16x8, w);
    }
}

// ---- pass1: from-zero superchunk partials (sc 0..2), wave-specialized ------
__global__ __launch_bounds__(512)
void rwkv5_pass1(const float* __restrict__ K, const float* __restrict__ V,
                 const float* __restrict__ TD, float* __restrict__ Buf) {
    __shared__ alignas(16) unsigned short KWs[2][4096], VSTs[2][4096];
    const int bh = blockIdx.x, sc = blockIdx.y;
    const int b = bh >> 5, h = bh & 31;
    const int tid = threadIdx.x, wid = tid >> 6, l = tid & 63;
    const int lo = l & 31, hi = l >> 5;
    // compute roles (wid 0..3)
    const int dhs = (wid >> 1) & 1, shs = wid & 1;
    const int dS = lo + 32 * dhs, sS = lo + 32 * shs;
    // stage roles (wid 4..7): 256 staging threads, 16 elems each
    const int sid = tid - 256;
    const int st = (sid & 255) >> 2, c16 = (sid & 3) * 16;
    const size_t tbase = ((size_t)b * cT + (size_t)sc * cSCL) * cTS + h * cS;
    const float *kb = K + tbase, *vb = V + tbase;

    float ipw[16];
    float tdL = 1.0f;
    if (wid >= 4) {
#pragma unroll
        for (int e = 0; e < 16; ++e) {
            const float l2 = hw_log2(TD[h * cS + c16 + e]);
            ipw[e] = hw_exp2(-(float)(st + 1) * l2);     // td^-(st+1)
        }
    } else {
        tdL = TD[h * cS + sS];
#pragma unroll
        for (int i = 0; i < 6; ++i) tdL *= tdL;          // td^64
    }

    float kx[16], vx[16];
    auto gload = [&](int cc) {
        const size_t off = ((size_t)(cc * cL + st)) * cTS + c16;
#pragma unroll
        for (int i = 0; i < 4; ++i) {
            *(float4*)&kx[i * 4] = *(const float4*)(kb + off + i * 4);
            *(float4*)&vx[i * 4] = *(const float4*)(vb + off + i * 4);
        }
    };
    auto tileWrite = [&](int bi) {
        const v2f* kx2  = (const v2f*)kx;
        const v2f* vx2  = (const v2f*)vx;
        const v2f* ipw2 = (const v2f*)ipw;
        u16x8 w;
#pragma unroll
        for (int hf = 0; hf < 2; ++hf) {
#pragma unroll
            for (int e2 = 0; e2 < 4; ++e2) {
                v2f m = kx2[hf * 4 + e2] * ipw2[hf * 4 + e2];
                w[2 * e2]     = bfb(m.x);
                w[2 * e2 + 1] = bfb(m.y);
            }
            stRow8(KWs[bi], st, c16 + hf * 8, w);
        }
        const v2f sc2 = {cScale, cScale};
#pragma unroll
        for (int e2 = 0; e2 < 8; ++e2) {
            v2f m = vx2[e2] * sc2;
            stElV16(VSTs[bi], c16 + 2 * e2,     st, bfb(m.x));
            stElV16(VSTs[bi], c16 + 2 * e2 + 1, st, bfb(m.y));
        }
    };

    f32x16 x;
#pragma unroll
    for (int i = 0; i < 16; ++i) x[i] = 0.f;

    if (wid >= 4) { gload(0); tileWrite(0); gload(1); }
    BARRIER();
#pragma unroll 1
    for (int c = 0; c < cNS; ++c) {
        const int cur = c & 1, nxt = cur ^ 1;
        if (wid < 4) {
            f32x16 w;
#pragma unroll
            for (int i = 0; i < 16; ++i) w[i] = 0.f;
            __builtin_amdgcn_s_setprio(1);
#pragma unroll
            for (int ks = 0; ks < 4; ++ks) {
                bf16x8 vaf = ldRowFragV(VSTs[cur], dS, ks * 16 + hi * 8);
                bf16x8 kcf = ldColFrag(KWs[cur], ks * 16 + hi * 8, sS);
                w = __builtin_amdgcn_mfma_f32_32x32x16_bf16(vaf, kcf, w, 0, 0, 0);
            }
            __builtin_amdgcn_s_setprio(0);
#pragma unroll
            for (int i = 0; i < 16; ++i) x[i] = tdL * (x[i] + w[i]);
        } else {
            if (c + 1 < cNS) tileWrite(nxt);
            if (c + 2 < cNS) gload(c + 2);
        }
        BARRIER();
    }
    if (wid < 4) {
        float* xp = Buf + ((size_t)bh * cSC + sc) * cS * cS;
#pragma unroll
        for (int r = 0; r < 16; ++r)
            xp[(size_t)sS * cS + crow(r, hi) + 32 * dhs] = x[r];
    }
}

// ---------------- pass2: propagate entry states (in place) ------------------
__global__ __launch_bounds__(256)
void rwkv5_pass2(const float* __restrict__ S2in, const float* __restrict__ TD,
                 float* __restrict__ Buf) {
    const int bh = blockIdx.x, h = bh & 31;
    const int t = threadIdx.x, s = t >> 2, db = (t & 3) * 16;
    float d = TD[h * cS + s];
#pragma unroll
    for (int i = 0; i < 10; ++i) d *= d;              // td^1024 = td^cSCL
    float4 x[4];
    const float* s0 = S2in + ((size_t)bh * cS + s) * cS + db;
#pragma unroll
    for (int i = 0; i < 4; ++i) {
        x[i] = *(const float4*)(s0 + i * 4);
        x[i].x *= cScale; x[i].y *= cScale; x[i].z *= cScale; x[i].w *= cScale;
    }
    for (int sc = 0; sc < cSC; ++sc) {
        float* base = Buf + (((size_t)bh * cSC + sc) * cS + s) * cS + db;
        float4 pr[4];
        if (sc < cSC - 1) {
#pragma unroll
            for (int i = 0; i < 4; ++i) pr[i] = *(const float4*)(base + i * 4);
        }
#pragma unroll
        for (int i = 0; i < 4; ++i) *(float4*)(base + i * 4) = x[i];
        if (sc < cSC - 1) {
#pragma unroll
            for (int i = 0; i < 4; ++i) {
                x[i].x = fmaf(d, x[i].x, pr[i].x);
                x[i].y = fmaf(d, x[i].y, pr[i].y);
                x[i].z = fmaf(d, x[i].z, pr[i].z);
                x[i].w = fmaf(d, x[i].w, pr[i].w);
            }
        }
    }
}

// ---------------- pass3: main compute ----------------------------------------
__global__ __launch_bounds__(512)
void rwkv5_pass3(const float* __restrict__ K, const float* __restrict__ V,
                 const float* __restrict__ R, const float* __restrict__ TF,
                 const float* __restrict__ TD, const float* __restrict__ Buf,
                 float* __restrict__ Out) {
    __shared__ alignas(16) unsigned short RWs[2][4096], KWs[2][4096],
                                          VSTs[2][4096];
    __shared__ alignas(16) u32x4 XTF[2][2][4][64];   // [buf][dh][ks][lane]
    __shared__ float DIAGs[2][64];
    const int u = blockIdx.x, bh = u >> 2, sc = u & 3;
    const int b = bh >> 5, h = bh & 31;
    const int tid = threadIdx.x, wid = tid >> 6, l = tid & 63;
    const int lo = l & 31, hi = l >> 5;
    const size_t tbase = ((size_t)b * cT + (size_t)sc * cSCL) * cTS + h * cS;
    const float *kb = K + tbase, *vb = V + tbase, *rb = R + tbase;
    float* ob = Out + tbase;

    // staging role: row st (timestep), 8 cols at sc8
    const int st = tid >> 3, sc8 = (tid & 7) * 8;
    float pwA[8], ipwB[8], tfv[8];
#pragma unroll
    for (int e = 0; e < 8; ++e) {
        const float l2 = hw_log2(TD[h * cS + sc8 + e]);
        pwA[e]  = hw_exp2((float)st * l2);            // td^st
        ipwB[e] = hw_exp2(-(float)(st + 1) * l2);     // td^-(st+1)
        tfv[e]  = TF[h * cS + sc8 + e];
    }
    float kx[8], vx[8], rx[8];
    auto gload = [&](int cc) {
        const size_t off = ((size_t)(cc * cL + st)) * cTS + sc8;
        *(float4*)&kx[0] = *(const float4*)(kb + off);
        *(float4*)&kx[4] = *(const float4*)(kb + off + 4);
        *(float4*)&vx[0] = *(const float4*)(vb + off);
        *(float4*)&vx[4] = *(const float4*)(vb + off + 4);
        *(float4*)&rx[0] = *(const float4*)(rb + off);
        *(float4*)&rx[4] = *(const float4*)(rb + off + 4);
    };
    auto tileWrite = [&](int bi) {
        const v2f* kx2  = (const v2f*)kx;
        const v2f* rx2  = (const v2f*)rx;
        const v2f* vx2  = (const v2f*)vx;
        const v2f* pwA2 = (const v2f*)pwA;
        const v2f* ipw2 = (const v2f*)ipwB;
        const v2f* tf2  = (const v2f*)tfv;
        u16x8 w;
#pragma unroll
        for (int e2 = 0; e2 < 4; ++e2) {
            v2f m = rx2[e2] * pwA2[e2];
            w[2 * e2]     = bfb(m.x);
            w[2 * e2 + 1] = bfb(m.y);
        }
        stRow8(RWs[bi], st, sc8, w);
#pragma unroll
        for (int e2 = 0; e2 < 4; ++e2) {
            v2f m = kx2[e2] * ipw2[e2];
            w[2 * e2]     = bfb(m.x);
            w[2 * e2 + 1] = bfb(m.y);
        }
        stRow8(KWs[bi], st, sc8, w);
        const v2f sc2 = {cScale, cScale};
#pragma unroll
        for (int e2 = 0; e2 < 4; ++e2) {
            v2f m = vx2[e2] * sc2;
            stElV16(VSTs[bi], sc8 + 2 * e2,     st, bfb(m.x));
            stElV16(VSTs[bi], sc8 + 2 * e2 + 1, st, bfb(m.y));
        }
        v2f p2 = {0.f, 0.f};
#pragma unroll
        for (int e2 = 0; e2 < 4; ++e2)
            p2 = (rx2[e2] * kx2[e2]) * tf2[e2] + p2;
        float p = p2.x + p2.y;
        p += __shfl_xor(p, 1, 64);
        p += __shfl_xor(p, 2, 64);
        p += __shfl_xor(p, 4, 64);
        if ((tid & 7) == 0) DIAGs[bi][st] = p;
    };

    // GEMM-wave roles (wid 0..3): out quadrant rows 32*ih.., cols 32*dh..
    const int ih = (wid >> 1) & 1, dh = wid & 1;
    // state-wave roles (wid 4..7): X quadrant s-rows 32*shs.., d-cols 32*dhs..
    const int shs = (wid >> 1) & 1, dhs = wid & 1;

    f32x16 x;
    float tdLr[16];
    if (wid >= 4) {
        const float* xin = Buf + ((size_t)bh * cSC + sc) * cS * cS;
#pragma unroll
        for (int r = 0; r < 16; ++r) {
            const int s = crow(r, hi) + 32 * shs;
            x[r] = xin[(size_t)s * cS + lo + 32 * dhs];
            float t = TD[h * cS + s];
#pragma unroll
            for (int i = 0; i < 6; ++i) t *= t;       // td^64
            tdLr[r] = t;
        }
        bf16x8 f0, f1;
        pack2(x, f0, f1);
        XTF[0][dhs][2 * shs][l]     = __builtin_bit_cast(u32x4, f0);
        XTF[0][dhs][2 * shs + 1][l] = __builtin_bit_cast(u32x4, f1);
    }
    gload(0); tileWrite(0); gload(1);
    BARRIER();

#pragma unroll 1
    for (int c = 0; c < cNS; ++c) {
        const int cur = c & 1, nxt = cur ^ 1;
        if (wid < 4) {
            // ---- A^T blocks in-register ----
            bf16x8 rwf[4];
#pragma unroll
            for (int ks = 0; ks < 4; ++ks)
                rwf[ks] = ldRowFrag(RWs[cur], lo + 32 * ih, ks * 16 + hi * 8);
            bf16x8 af0, af1, af2, af3;
            if (ih == 1) {                     // unmasked block j in [0,32)
                f32x16 aU;
#pragma unroll
                for (int i = 0; i < 16; ++i) aU[i] = 0.f;
                __builtin_amdgcn_s_setprio(1);
#pragma unroll
                for (int ks = 0; ks < 4; ++ks) {
                    bf16x8 kwf = ldRowFrag(KWs[cur], lo, ks * 16 + hi * 8);
                    aU = __builtin_amdgcn_mfma_f32_32x32x16_bf16(kwf, rwf[ks], aU, 0, 0, 0);
                }
                __builtin_amdgcn_s_setprio(0);
                pack2(aU, af0, af1);
            }
            f32x16 aM;                         // diagonal block j in [32ih, 32ih+32)
#pragma unroll
            for (int i = 0; i < 16; ++i) aM[i] = 0.f;
            __builtin_amdgcn_s_setprio(1);
#pragma unroll
            for (int ks = 0; ks < 4; ++ks) {
                bf16x8 kwf = ldRowFrag(KWs[cur], lo + 32 * ih, ks * 16 + hi * 8);
                aM = __builtin_amdgcn_mfma_f32_32x32x16_bf16(kwf, rwf[ks], aM, 0, 0, 0);
            }
            __builtin_amdgcn_s_setprio(0);
            const float diagv = DIAGs[cur][lo + 32 * ih];
#pragma unroll
            for (int r = 0; r < 16; ++r) {
                const int cr = crow(r, hi);
                aM[r] = (lo > cr) ? aM[r] : ((lo == cr) ? diagv : 0.f);
            }
            if (ih == 1) pack2(aM, af2, af3);
            else         pack2(aM, af0, af1);
            // ---- out = A@VS + RW@X ----
            f32x16 o;
#pragma unroll
            for (int i = 0; i < 16; ++i) o[i] = 0.f;
            __builtin_amdgcn_s_setprio(1);
            o = __builtin_amdgcn_mfma_f32_32x32x16_bf16(
                af0, ldRowFragV(VSTs[cur], lo + 32 * dh, 0 * 16 + hi * 8), o, 0, 0, 0);
            o = __builtin_amdgcn_mfma_f32_32x32x16_bf16(
                af1, ldRowFragV(VSTs[cur], lo + 32 * dh, 1 * 16 + hi * 8), o, 0, 0, 0);
            if (ih == 1) {
                o = __builtin_amdgcn_mfma_f32_32x32x16_bf16(
                    af2, ldRowFragV(VSTs[cur], lo + 32 * dh, 2 * 16 + hi * 8), o, 0, 0, 0);
                o = __builtin_amdgcn_mfma_f32_32x32x16_bf16(
                    af3, ldRowFragV(VSTs[cur], lo + 32 * dh, 3 * 16 + hi * 8), o, 0, 0, 0);
            }
#pragma unroll
            for (int ks = 0; ks < 4; ++ks) {
                bf16x8 xf = __builtin_bit_cast(bf16x8, XTF[cur][dh][ks][l]);
                o = __builtin_amdgcn_mfma_f32_32x32x16_bf16(rwf[ks], xf, o, 0, 0, 0);
            }
            __builtin_amdgcn_s_setprio(0);
            const int t0 = c * cL;
#pragma unroll
            for (int r = 0; r < 16; ++r)
                ob[(size_t)(t0 + crow(r, hi) + 32 * ih) * cTS + 32 * dh + lo] = o[r];
        } else {
            // ---- state chain: w = KW^T @ VS, x in (lane=d, reg=s) layout ----
            f32x16 w;
#pragma unroll
            for (int i = 0; i < 16; ++i) w[i] = 0.f;
            __builtin_amdgcn_s_setprio(1);
#pragma unroll
            for (int ks = 0; ks < 4; ++ks) {
                bf16x8 kcf = ldColFrag(KWs[cur], ks * 16 + hi * 8, lo + 32 * shs);
                bf16x8 vaf = ldRowFragV(VSTs[cur], lo + 32 * dhs, ks * 16 + hi * 8);
                w = __builtin_amdgcn_mfma_f32_32x32x16_bf16(kcf, vaf, w, 0, 0, 0);
            }
            __builtin_amdgcn_s_setprio(0);
#pragma unroll
            for (int i = 0; i < 16; ++i) x[i] = tdLr[i] * (x[i] + w[i]);
            if (c + 1 < cNS) {
                bf16x8 f0, f1;
                pack2(x, f0, f1);
                XTF[nxt][dhs][2 * shs][l]     = __builtin_bit_cast(u32x4, f0);
                XTF[nxt][dhs][2 * shs + 1][l] = __builtin_bit_cast(u32x4, f1);
            }
        }
        if (c + 1 < cNS) tileWrite(nxt);
        if (c + 2 < cNS) gload(c + 2);
        BARRIER();
    }
    if (wid >= 4 && sc == cSC - 1) {
        float* o2 = Out + (size_t)cB * cT * cTS + (size_t)bh * cS * cS;
#pragma unroll
        for (int r = 0; r < 16; ++r) {
            const int s = crow(r, hi) + 32 * shs;
            o2[(size_t)s * cS + lo + 32 * dhs] = x[r] * 128.0f;
        }
    }
}

extern "C" void kernel_launch(void* const* d_in, const int* in_sizes, int n_in,
                              void* d_out, int out_size, void* d_ws,
                              size_t ws_size, hipStream_t stream) {
    const float* K    = (const float*)d_in[0];
    const float* V    = (const float*)d_in[1];
    const float* R    = (const float*)d_in[2];
    const float* S2in = (const float*)d_in[3];
    const float* TF   = (const float*)d_in[4];
    const float* TD   = (const float*)d_in[5];
    float* OutP = (float*)d_out;
    float* Buf  = (float*)d_ws;            // [128][4][64][64] f32 = 8.4 MB
    (void)in_sizes; (void)n_in; (void)ws_size; (void)out_size;

    rwkv5_pass1<<<dim3(cBH, cSC - 1), dim3(512), 0, stream>>>(K, V, TD, Buf);
    rwkv5_pass2<<<dim3(cBH), dim3(256), 0, stream>>>(S2in, TD, Buf);
    rwkv5_pass3<<<dim3(cBH * cSC), dim3(512), 0, stream>>>(K, V, R, TF, TD,
                                                           Buf, OutP);
}